// Round 1
// baseline (50618.564 us; speedup 1.0000x reference)
//
#include <hip/hip_runtime.h>
#include <hip/hip_bf16.h>
#include <cstdio>
#include <cstdint>

// MultilayerGRU: B=32, S=512, I=H=O=1024, L=2
// Strategy:
//   1) cast weights + x to bf16 (ws)
//   2) big GEMM: layer0 input projections Az/Ar/Ag = x @ W{z,r,g}x0^T + b  (bf16, MFMA)
//   3) persistent-kernel recurrence for layer 0 (512 steps, 2 grid barriers/step),
//      writes h0 history (bf16)
//   4) big GEMM: layer1 input projections from h0 history (reuses Az/Ar/Ag)
//   5) persistent-kernel recurrence for layer 1, writes h1 history
//   6) big GEMM: Y = h1_hist @ Wo^T + bo -> d_out (fp32)
//   7) final hidden state write

typedef float f32x4 __attribute__((ext_vector_type(4)));
typedef __bf16 bf16x8 __attribute__((ext_vector_type(8)));
typedef unsigned short u16;

#define AS1 __attribute__((address_space(1)))
#define AS3 __attribute__((address_space(3)))

__device__ inline u16 f2b(float f) {
  __hip_bfloat16 h = __float2bfloat16(f);
  return *reinterpret_cast<u16*>(&h);
}
__device__ inline float b2f(u16 u) {
  __hip_bfloat16 h;
  *reinterpret_cast<u16*>(&h) = u;
  return __bfloat162float(h);
}
__device__ inline bf16x8 ld8(const u16* p) {
  return *reinterpret_cast<const bf16x8*>(p);
}
__device__ inline f32x4 mfma16(bf16x8 a, bf16x8 b, f32x4 c) {
  return __builtin_amdgcn_mfma_f32_16x16x32_bf16(a, b, c, 0, 0, 0);
}

__device__ inline void gload_lds16(const void* g, void* l) {
  __builtin_amdgcn_global_load_lds((const AS1 void*)g, (AS3 void*)l, 16, 0, 0);
}

// device-scope grid barrier (monotone counter, one arrival per block)
__device__ inline void gridbar(unsigned* ctr, unsigned nblk, unsigned& phase) {
  __syncthreads();
  if (threadIdx.x == 0) {
    __threadfence();  // release: flush this XCD's dirty L2 to LLC
    __hip_atomic_fetch_add(ctr, 1u, __ATOMIC_RELAXED, __HIP_MEMORY_SCOPE_AGENT);
    ++phase;
    unsigned tgt = phase * nblk;
    while (__hip_atomic_load(ctr, __ATOMIC_RELAXED, __HIP_MEMORY_SCOPE_AGENT) < tgt)
      __builtin_amdgcn_s_sleep(1);
    __threadfence();  // acquire: invalidate stale L1/L2 lines
  }
  __syncthreads();
}

// ---------------- elementwise helpers ----------------

__global__ void castk(const float* __restrict__ src, u16* __restrict__ dst, int n) {
  int i = blockIdx.x * 256 + threadIdx.x;
  if (i < n) dst[i] = f2b(src[i]);
}

__global__ void init_h(const float* __restrict__ h0, float* __restrict__ h32_0,
                       float* __restrict__ h32_1, u16* __restrict__ hbf_0,
                       u16* __restrict__ hbf_1) {
  int i = blockIdx.x * 256 + threadIdx.x;
  if (i < 32 * 1024) {
    int b = i >> 10, j = i & 1023;
    float v0 = h0[(b * 2 + 0) * 1024 + j];
    float v1 = h0[(b * 2 + 1) * 1024 + j];
    h32_0[i] = v0; hbf_0[i] = f2b(v0);
    h32_1[i] = v1; hbf_1[i] = f2b(v1);
  }
}

__global__ void final_h(const float* __restrict__ h32_0, const float* __restrict__ h32_1,
                        float* __restrict__ out) {
  int i = blockIdx.x * 256 + threadIdx.x;
  if (i < 32 * 1024) {
    int b = i >> 10, j = i & 1023;
    out[(b * 2 + 0) * 1024 + j] = h32_0[i];
    out[(b * 2 + 1) * 1024 + j] = h32_1[i];
  }
}

// ---------------- big NT GEMM: C[m,n] = sum_k A[m,k]*B[n,k] + bias[n] ----------------
// A: bf16 [M,K] row-major, B: bf16 [N,K] row-major. 128x128 tile, BK=32, 4 waves.

template <int STORE_BF16>
__global__ __launch_bounds__(256, 2) void gemm_nt(const u16* __restrict__ A,
                                                  const u16* __restrict__ B,
                                                  const float* __restrict__ bias,
                                                  void* __restrict__ Cout,
                                                  int M, int N, int K) {
  __shared__ __align__(16) u16 As[128 * 32];
  __shared__ __align__(16) u16 Bs[128 * 32];
  const int tid = threadIdx.x;
  const int lane = tid & 63;
  const int wave = tid >> 6;
  const int tilesN = N >> 7;
  const int bm = blockIdx.x / tilesN, bn = blockIdx.x % tilesN;
  const int wr = (wave >> 1) << 6, wc = (wave & 1) << 6;
  const int la = lane & 15, kg = lane >> 4;
  f32x4 acc[4][4] = {};
  const int srow = tid >> 2, skoff = (tid & 3) << 3;
  const u16* Ap = A + (size_t)(bm * 128 + srow) * K + skoff;
  const u16* Bp = B + (size_t)(bn * 128 + srow) * K + skoff;
  for (int k0 = 0; k0 < K; k0 += 32) {
    gload_lds16(Ap + k0,            As + tid * 8);
    gload_lds16(Ap + (size_t)64 * K + k0, As + 2048 + tid * 8);
    gload_lds16(Bp + k0,            Bs + tid * 8);
    gload_lds16(Bp + (size_t)64 * K + k0, Bs + 2048 + tid * 8);
    __syncthreads();  // drains the global_load_lds (vmcnt) too
    bf16x8 af[4], bfr[4];
#pragma unroll
    for (int i = 0; i < 4; ++i) af[i] = ld8(As + (wr + i * 16 + la) * 32 + kg * 8);
#pragma unroll
    for (int j = 0; j < 4; ++j) bfr[j] = ld8(Bs + (wc + j * 16 + la) * 32 + kg * 8);
#pragma unroll
    for (int i = 0; i < 4; ++i)
#pragma unroll
      for (int j = 0; j < 4; ++j)
        acc[i][j] = mfma16(af[i], bfr[j], acc[i][j]);
    __syncthreads();
  }
  const int rbase = bm * 128 + wr + kg * 4;
  const int cbase = bn * 128 + wc + la;
#pragma unroll
  for (int i = 0; i < 4; ++i) {
#pragma unroll
    for (int j = 0; j < 4; ++j) {
      int col = cbase + j * 16;
      float bv = bias[col];
#pragma unroll
      for (int e = 0; e < 4; ++e) {
        int row = rbase + i * 16 + e;
        float v = acc[i][j][e] + bv;
        if (STORE_BF16)
          ((u16*)Cout)[(size_t)row * N + col] = f2b(v);
        else
          ((float*)Cout)[(size_t)row * N + col] = v;
      }
    }
  }
}

// ---------------- persistent GRU layer recurrence ----------------
// 256 blocks x 64 threads (one wave per block).
// Stage 1 (256 waves): gate z (wid<128) / gate r (wid>=128); each wave one 16x16 tile
//   of sigmoid(A_add + h @ W^T). z -> zbuf (fp32); r -> rhbf = bf16(r * h32).
// Stage 2 (128 waves): g = tanh(Ag_add + rh @ Wg^T); h' = (1-z)h + z g;
//   writes h32, hbf, hist[t].

__global__ __launch_bounds__(64) void gru_layer(
    const u16* __restrict__ Wz, const u16* __restrict__ Wr, const u16* __restrict__ Wg,
    const u16* __restrict__ Az, const u16* __restrict__ Ar, const u16* __restrict__ Ag,
    u16* __restrict__ hist, float* __restrict__ h32, u16* __restrict__ hbf,
    float* __restrict__ zbuf, u16* __restrict__ rhbf, unsigned* ctr, int S) {
  const int wid = blockIdx.x;     // 0..255
  const int lane = threadIdx.x;   // 0..63
  const int la = lane & 15, kg = lane >> 4;
  const int colT = wid & 63;
  const int rt = (wid >> 6) & 1;
  const int gate = wid >> 7;  // 0 = z, 1 = r  (stage 1)
  const int col = colT * 16 + la;
  unsigned phase = 0;

  const u16* W1 = gate ? Wr : Wz;
  const u16* A1 = gate ? Ar : Az;
  const u16* w1p = W1 + (size_t)col * 1024 + kg * 8;
  const u16* wgp = Wg + (size_t)col * 1024 + kg * 8;
  const int hrow_off = (rt * 16 + la) * 1024 + kg * 8;

  for (int t = 0; t < S; ++t) {
    // ---- stage 1 ----
    {
      const u16* hp = hbf + hrow_off;
      f32x4 acc = {0.f, 0.f, 0.f, 0.f};
#pragma unroll 8
      for (int ks = 0; ks < 32; ++ks)
        acc = mfma16(ld8(hp + ks * 32), ld8(w1p + ks * 32), acc);
#pragma unroll
      for (int e = 0; e < 4; ++e) {
        int b = rt * 16 + kg * 4 + e;
        float pre = acc[e] + b2f(A1[((size_t)(b * S + t)) * 1024 + col]);
        float v = 1.f / (1.f + __expf(-pre));
        if (gate == 0)
          zbuf[b * 1024 + col] = v;
        else
          rhbf[b * 1024 + col] = f2b(v * h32[b * 1024 + col]);
      }
    }
    gridbar(ctr, 256, phase);
    // ---- stage 2 ----
    if (wid < 128) {
      const u16* ap = rhbf + hrow_off;
      f32x4 acc = {0.f, 0.f, 0.f, 0.f};
#pragma unroll 8
      for (int ks = 0; ks < 32; ++ks)
        acc = mfma16(ld8(ap + ks * 32), ld8(wgp + ks * 32), acc);
#pragma unroll
      for (int e = 0; e < 4; ++e) {
        int b = rt * 16 + kg * 4 + e;
        float g = tanhf(acc[e] + b2f(Ag[((size_t)(b * S + t)) * 1024 + col]));
        float z = zbuf[b * 1024 + col];
        float hn = (1.f - z) * h32[b * 1024 + col] + z * g;
        h32[b * 1024 + col] = hn;
        u16 hb = f2b(hn);
        hbf[b * 1024 + col] = hb;
        hist[((size_t)(b * S + t)) * 1024 + col] = hb;
      }
    }
    gridbar(ctr, 256, phase);
  }
}

// ---------------- host ----------------

extern "C" void kernel_launch(void* const* d_in, const int* in_sizes, int n_in,
                              void* d_out, int out_size, void* d_ws, size_t ws_size,
                              hipStream_t stream) {
  (void)in_sizes; (void)n_in; (void)out_size;
  const float* x   = (const float*)d_in[0];
  const float* h0  = (const float*)d_in[1];
  const float* Wzx = (const float*)d_in[2];
  const float* bz  = (const float*)d_in[3];
  const float* Wzh = (const float*)d_in[4];
  const float* Wrx = (const float*)d_in[5];
  const float* br  = (const float*)d_in[6];
  const float* Wrh = (const float*)d_in[7];
  const float* Wgx = (const float*)d_in[8];
  const float* bg  = (const float*)d_in[9];
  const float* Wgh = (const float*)d_in[10];
  const float* Wo  = (const float*)d_in[11];
  const float* bo  = (const float*)d_in[12];
  float* out = (float*)d_out;
  char* ws = (char*)d_ws;

  const size_t MB = 1024 * 1024;
  size_t o = 256;
  u16* wWzx = (u16*)(ws + o); o += 4 * MB;   // [L=2][1024][1024] bf16
  u16* wWzh = (u16*)(ws + o); o += 4 * MB;
  u16* wWrx = (u16*)(ws + o); o += 4 * MB;
  u16* wWrh = (u16*)(ws + o); o += 4 * MB;
  u16* wWgx = (u16*)(ws + o); o += 4 * MB;
  u16* wWgh = (u16*)(ws + o); o += 4 * MB;
  u16* wWo  = (u16*)(ws + o); o += 2 * MB;
  u16* Az    = (u16*)(ws + o); o += 32 * MB;  // [16384,1024] bf16 (reused for layer1)
  u16* Ar    = (u16*)(ws + o); o += 32 * MB;
  u16* Ag    = (u16*)(ws + o); o += 32 * MB;
  u16* hist0 = (u16*)(ws + o); o += 32 * MB;
  u16* xbf   = (u16*)(ws + o); o += 32 * MB;  // x bf16; later reused as hist1
  float* h32_0 = (float*)(ws + o); o += 131072;
  float* h32_1 = (float*)(ws + o); o += 131072;
  u16* hbf_0 = (u16*)(ws + o); o += 65536;
  u16* hbf_1 = (u16*)(ws + o); o += 65536;
  float* zbuf = (float*)(ws + o); o += 131072;
  u16* rhbf = (u16*)(ws + o); o += 65536;

  fprintf(stderr, "[gru] ws_size=%zu needed=%zu\n", ws_size, o);
  if (ws_size < o) {
    fprintf(stderr, "[gru] INSUFFICIENT WORKSPACE - aborting\n");
    return;
  }
  unsigned* ctr0 = (unsigned*)(ws + 0);
  unsigned* ctr1 = (unsigned*)(ws + 128);
  hipMemsetAsync(ws, 0, 256, stream);

  // casts
  castk<<<dim3(8192), dim3(256), 0, stream>>>(Wzx, wWzx, 2097152);
  castk<<<dim3(8192), dim3(256), 0, stream>>>(Wzh, wWzh, 2097152);
  castk<<<dim3(8192), dim3(256), 0, stream>>>(Wrx, wWrx, 2097152);
  castk<<<dim3(8192), dim3(256), 0, stream>>>(Wrh, wWrh, 2097152);
  castk<<<dim3(8192), dim3(256), 0, stream>>>(Wgx, wWgx, 2097152);
  castk<<<dim3(8192), dim3(256), 0, stream>>>(Wgh, wWgh, 2097152);
  castk<<<dim3(4096), dim3(256), 0, stream>>>(Wo, wWo, 1048576);
  castk<<<dim3(65536), dim3(256), 0, stream>>>(x, xbf, 16777216);
  init_h<<<dim3(128), dim3(256), 0, stream>>>(h0, h32_0, h32_1, hbf_0, hbf_1);

  // layer0 input projections
  gemm_nt<1><<<dim3(1024), dim3(256), 0, stream>>>(xbf, wWzx, bz, Az, 16384, 1024, 1024);
  gemm_nt<1><<<dim3(1024), dim3(256), 0, stream>>>(xbf, wWrx, br, Ar, 16384, 1024, 1024);
  gemm_nt<1><<<dim3(1024), dim3(256), 0, stream>>>(xbf, wWgx, bg, Ag, 16384, 1024, 1024);

  // layer0 recurrence
  gru_layer<<<dim3(256), dim3(64), 0, stream>>>(wWzh, wWrh, wWgh, Az, Ar, Ag, hist0,
                                                h32_0, hbf_0, zbuf, rhbf, ctr0, 512);

  // layer1 input projections (from h0 history)
  gemm_nt<1><<<dim3(1024), dim3(256), 0, stream>>>(hist0, wWzx + 1048576, bz + 1024, Az, 16384, 1024, 1024);
  gemm_nt<1><<<dim3(1024), dim3(256), 0, stream>>>(hist0, wWrx + 1048576, br + 1024, Ar, 16384, 1024, 1024);
  gemm_nt<1><<<dim3(1024), dim3(256), 0, stream>>>(hist0, wWgx + 1048576, bg + 1024, Ag, 16384, 1024, 1024);

  // layer1 recurrence (hist1 lives in xbf region - x no longer needed)
  gru_layer<<<dim3(256), dim3(64), 0, stream>>>(wWzh + 1048576, wWrh + 1048576, wWgh + 1048576,
                                                Az, Ar, Ag, xbf, h32_1, hbf_1, zbuf, rhbf,
                                                ctr1, 512);

  // output projection
  gemm_nt<0><<<dim3(1024), dim3(256), 0, stream>>>(xbf, wWo, bo, out, 16384, 1024, 1024);

  // final hidden states
  final_h<<<dim3(128), dim3(256), 0, stream>>>(h32_0, h32_1, out + 16777216);
}

// Round 2
// 14969.928 us; speedup vs baseline: 3.3813x; 3.3813x over previous
//
#include <hip/hip_runtime.h>
#include <hip/hip_bf16.h>
#include <cstdio>
#include <cstdint>

// MultilayerGRU: B=32, S=512, I=H=O=1024, L=2
// R2: fence-free epoch-flag sync (agent-scope atomics, no buffer_inv),
//     LDS staging of h/rh via global_load_lds aux=SC0|SC1, per-rt sync domains,
//     z/r parallel waves + split-K g. Weights stay L2-resident all dispatch.

typedef float f32x4 __attribute__((ext_vector_type(4)));
typedef __bf16 bf16x8 __attribute__((ext_vector_type(8)));
typedef unsigned short u16;

#define AS1 __attribute__((address_space(1)))
#define AS3 __attribute__((address_space(3)))

__device__ inline u16 f2b(float f) {
  __hip_bfloat16 h = __float2bfloat16(f);
  return *reinterpret_cast<u16*>(&h);
}
__device__ inline float b2f(u16 u) {
  __hip_bfloat16 h;
  *reinterpret_cast<u16*>(&h) = u;
  return __bfloat162float(h);
}
__device__ inline bf16x8 ld8(const u16* p) {
  return *reinterpret_cast<const bf16x8*>(p);
}
__device__ inline f32x4 mfma16(bf16x8 a, bf16x8 b, f32x4 c) {
  return __builtin_amdgcn_mfma_f32_16x16x32_bf16(a, b, c, 0, 0, 0);
}

// plain (L2-cacheable) global->LDS DMA, 16B/lane
__device__ inline void gload_lds16(const void* g, void* l) {
  __builtin_amdgcn_global_load_lds((const AS1 void*)g, (AS3 void*)l, 16, 0, 0);
}
// agent-coherent global->LDS DMA: CPol SC0(1)|SC1(16) bypasses stale L1/L2
__device__ inline void gload_lds16c(const void* g, void* l) {
  __builtin_amdgcn_global_load_lds((const AS1 void*)g, (AS3 void*)l, 16, 0, 0x11);
}

// relaxed agent-scope (LLC write-through) u16 store
__device__ inline void st16(u16* p, u16 v) {
  __hip_atomic_store(p, v, __ATOMIC_RELAXED, __HIP_MEMORY_SCOPE_AGENT);
}

// 64 lanes watch 64 packed epoch flags; exit when all >= target
__device__ inline void poll64(unsigned* f, unsigned target, int lane) {
  unsigned* p = f + lane;
  while (true) {
    unsigned v = __hip_atomic_load(p, __ATOMIC_RELAXED, __HIP_MEMORY_SCOPE_AGENT);
    if (__all((int)(v >= target))) break;
    __builtin_amdgcn_s_sleep(1);
  }
}

// ---------------- elementwise helpers ----------------

__global__ void castk(const float* __restrict__ src, u16* __restrict__ dst, int n) {
  int i = blockIdx.x * 256 + threadIdx.x;
  if (i < n) dst[i] = f2b(src[i]);
}

__global__ void init_h(const float* __restrict__ h0, float* __restrict__ h32_0,
                       float* __restrict__ h32_1, u16* __restrict__ hbf_0,
                       u16* __restrict__ hbf_1) {
  int i = blockIdx.x * 256 + threadIdx.x;
  if (i < 32 * 1024) {
    int b = i >> 10, j = i & 1023;
    float v0 = h0[(b * 2 + 0) * 1024 + j];
    float v1 = h0[(b * 2 + 1) * 1024 + j];
    h32_0[i] = v0; hbf_0[i] = f2b(v0);
    h32_1[i] = v1; hbf_1[i] = f2b(v1);
  }
}

__global__ void final_h(const float* __restrict__ h32_0, const float* __restrict__ h32_1,
                        float* __restrict__ out) {
  int i = blockIdx.x * 256 + threadIdx.x;
  if (i < 32 * 1024) {
    int b = i >> 10, j = i & 1023;
    out[(b * 2 + 0) * 1024 + j] = h32_0[i];
    out[(b * 2 + 1) * 1024 + j] = h32_1[i];
  }
}

// ---------------- big NT GEMM: C[m,n] = sum_k A[m,k]*B[n,k] + bias[n] ----------------

template <int STORE_BF16>
__global__ __launch_bounds__(256, 2) void gemm_nt(const u16* __restrict__ A,
                                                  const u16* __restrict__ B,
                                                  const float* __restrict__ bias,
                                                  void* __restrict__ Cout,
                                                  int M, int N, int K) {
  __shared__ __align__(16) u16 As[128 * 32];
  __shared__ __align__(16) u16 Bs[128 * 32];
  const int tid = threadIdx.x;
  const int lane = tid & 63;
  const int wave = tid >> 6;
  const int tilesN = N >> 7;
  const int bm = blockIdx.x / tilesN, bn = blockIdx.x % tilesN;
  const int wr = (wave >> 1) << 6, wc = (wave & 1) << 6;
  const int la = lane & 15, kg = lane >> 4;
  f32x4 acc[4][4] = {};
  const int srow = tid >> 2, skoff = (tid & 3) << 3;
  const u16* Ap = A + (size_t)(bm * 128 + srow) * K + skoff;
  const u16* Bp = B + (size_t)(bn * 128 + srow) * K + skoff;
  for (int k0 = 0; k0 < K; k0 += 32) {
    gload_lds16(Ap + k0,            As + tid * 8);
    gload_lds16(Ap + (size_t)64 * K + k0, As + 2048 + tid * 8);
    gload_lds16(Bp + k0,            Bs + tid * 8);
    gload_lds16(Bp + (size_t)64 * K + k0, Bs + 2048 + tid * 8);
    __syncthreads();
    bf16x8 af[4], bfr[4];
#pragma unroll
    for (int i = 0; i < 4; ++i) af[i] = ld8(As + (wr + i * 16 + la) * 32 + kg * 8);
#pragma unroll
    for (int j = 0; j < 4; ++j) bfr[j] = ld8(Bs + (wc + j * 16 + la) * 32 + kg * 8);
#pragma unroll
    for (int i = 0; i < 4; ++i)
#pragma unroll
      for (int j = 0; j < 4; ++j)
        acc[i][j] = mfma16(af[i], bfr[j], acc[i][j]);
    __syncthreads();
  }
  const int rbase = bm * 128 + wr + kg * 4;
  const int cbase = bn * 128 + wc + la;
#pragma unroll
  for (int i = 0; i < 4; ++i) {
#pragma unroll
    for (int j = 0; j < 4; ++j) {
      int col = cbase + j * 16;
      float bv = bias[col];
#pragma unroll
      for (int e = 0; e < 4; ++e) {
        int row = rbase + i * 16 + e;
        float v = acc[i][j][e] + bv;
        if (STORE_BF16)
          ((u16*)Cout)[(size_t)row * N + col] = f2b(v);
        else
          ((float*)Cout)[(size_t)row * N + col] = v;
      }
    }
  }
}

// ---------------- persistent GRU layer recurrence, v2 ----------------
// 128 blocks x 128 threads. Block = (rt = blockIdx>>6, colT = blockIdx&63):
// owns the 16x16 tile rows [rt*16,+16) x cols [colT*16,+16).
// Stage1: wave0 -> z tile (into LDS zloc), wave1 -> r tile -> rhbf (agent store) + flag.
// Stage2: both waves split K=1024 of g; wave0 reduces, updates h, stores hbf + flag.
// Sync: per-rt 64-entry epoch flag arrays, polled 1 flag/lane. No fences ->
// per-XCD L2 keeps Wz/Wr/Wg resident across all 512 steps.

__global__ __launch_bounds__(128) void gru_layer2(
    const u16* __restrict__ Wz, const u16* __restrict__ Wr, const u16* __restrict__ Wg,
    const u16* __restrict__ Az, const u16* __restrict__ Ar, const u16* __restrict__ Ag,
    u16* __restrict__ hist, float* __restrict__ h32g, u16* __restrict__ hbf,
    u16* __restrict__ rhbf, unsigned* __restrict__ flags, int S) {
  __shared__ __align__(16) u16 LDSh[16 * 1024];  // staged h (stage1) / rh (stage2) rows
  __shared__ float zloc[256];    // z tile, idx (row)*16+col
  __shared__ float h32loc[256];  // fp32 master h tile
  __shared__ float part[256];    // wave1's split-K partial, idx lane*4+e
  const int tid = threadIdx.x, wave = tid >> 6, lane = tid & 63;
  const int la = lane & 15, kg = lane >> 4;
  const int rt = blockIdx.x >> 6, colT = blockIdx.x & 63;
  const int col = colT * 16 + la;
  unsigned* fl1 = flags + rt * 128;       // stage1 (rhbf ready) epochs [64]
  unsigned* fl2 = flags + rt * 128 + 64;  // stage2 (h ready) epochs [64]

  for (int i = tid; i < 256; i += 128)
    h32loc[i] = h32g[(rt * 16 + (i >> 4)) * 1024 + colT * 16 + (i & 15)];
  __syncthreads();

  const u16* w1p = (wave ? Wr : Wz) + (size_t)col * 1024 + kg * 8;
  const u16* wgp = Wg + (size_t)col * 1024 + wave * 512 + kg * 8;
  const u16* A1 = wave ? Ar : Az;
  const u16* hsrc = hbf + rt * 16 * 1024;
  const u16* rsrc = rhbf + rt * 16 * 1024;

  for (int t = 0; t < S; ++t) {
    // ---- stage 1: z (wave0) and r (wave1) ----
    poll64(fl2, (unsigned)t, lane);  // h(t-1) fully published in this rt group
#pragma unroll
    for (int i = 0; i < 16; ++i)
      gload_lds16c(hsrc + (i * 128 + tid) * 8, LDSh + (i * 128 + tid) * 8);
    __syncthreads();  // drains vmcnt incl. lds-dma
    float a1v[4];
#pragma unroll
    for (int e = 0; e < 4; ++e)
      a1v[e] = b2f(A1[(size_t)((rt * 16 + kg * 4 + e) * S + t) * 1024 + col]);
    f32x4 acc = {0.f, 0.f, 0.f, 0.f};
#pragma unroll 8
    for (int ks = 0; ks < 32; ++ks)
      acc = mfma16(ld8(LDSh + la * 1024 + ks * 32 + kg * 8), ld8(w1p + ks * 32), acc);
    if (wave == 0) {
#pragma unroll
      for (int e = 0; e < 4; ++e)
        zloc[(kg * 4 + e) * 16 + la] = 1.f / (1.f + __expf(-(acc[e] + a1v[e])));
    } else {
#pragma unroll
      for (int e = 0; e < 4; ++e) {
        int li = (kg * 4 + e) * 16 + la;
        float rv = 1.f / (1.f + __expf(-(acc[e] + a1v[e])));
        st16(&rhbf[(rt * 16 + kg * 4 + e) * 1024 + col], f2b(rv * h32loc[li]));
      }
      if (lane == 0)  // release waits this wave's vmcnt+lgkmcnt -> tile published
        __hip_atomic_store(&fl1[colT], (unsigned)(t + 1), __ATOMIC_RELEASE,
                           __HIP_MEMORY_SCOPE_AGENT);
    }
    // ---- stage 2: g (split-K over both waves) + h update (wave0) ----
    poll64(fl1, (unsigned)(t + 1), lane);  // all rh tiles of this rt group ready
#pragma unroll
    for (int i = 0; i < 16; ++i)
      gload_lds16c(rsrc + (i * 128 + tid) * 8, LDSh + (i * 128 + tid) * 8);
    __syncthreads();
    float agv[4];
#pragma unroll
    for (int e = 0; e < 4; ++e)
      agv[e] = b2f(Ag[(size_t)((rt * 16 + kg * 4 + e) * S + t) * 1024 + col]);
    f32x4 acc2 = {0.f, 0.f, 0.f, 0.f};
#pragma unroll 8
    for (int ks = 0; ks < 16; ++ks)
      acc2 = mfma16(ld8(LDSh + la * 1024 + wave * 512 + ks * 32 + kg * 8),
                    ld8(wgp + ks * 32), acc2);
    if (wave == 1) {
#pragma unroll
      for (int e = 0; e < 4; ++e) part[lane * 4 + e] = acc2[e];
    }
    __syncthreads();
    if (wave == 0) {
#pragma unroll
      for (int e = 0; e < 4; ++e) {
        int li = (kg * 4 + e) * 16 + la;
        float g = tanhf(acc2[e] + part[lane * 4 + e] + agv[e]);
        float z = zloc[li];
        float hn = (1.f - z) * h32loc[li] + z * g;
        h32loc[li] = hn;
        u16 hb = f2b(hn);
        st16(&hbf[(rt * 16 + kg * 4 + e) * 1024 + col], hb);
        st16(&hist[(size_t)((rt * 16 + kg * 4 + e) * S + t) * 1024 + col], hb);
        if (t == S - 1) h32g[(rt * 16 + kg * 4 + e) * 1024 + col] = hn;
      }
      if (lane == 0)
        __hip_atomic_store(&fl2[colT], (unsigned)(t + 1), __ATOMIC_RELEASE,
                           __HIP_MEMORY_SCOPE_AGENT);
    }
    __syncthreads();
  }
}

// ---------------- host ----------------

extern "C" void kernel_launch(void* const* d_in, const int* in_sizes, int n_in,
                              void* d_out, int out_size, void* d_ws, size_t ws_size,
                              hipStream_t stream) {
  (void)in_sizes; (void)n_in; (void)out_size;
  const float* x   = (const float*)d_in[0];
  const float* h0  = (const float*)d_in[1];
  const float* Wzx = (const float*)d_in[2];
  const float* bz  = (const float*)d_in[3];
  const float* Wzh = (const float*)d_in[4];
  const float* Wrx = (const float*)d_in[5];
  const float* br  = (const float*)d_in[6];
  const float* Wrh = (const float*)d_in[7];
  const float* Wgx = (const float*)d_in[8];
  const float* bg  = (const float*)d_in[9];
  const float* Wgh = (const float*)d_in[10];
  const float* Wo  = (const float*)d_in[11];
  const float* bo  = (const float*)d_in[12];
  float* out = (float*)d_out;
  char* ws = (char*)d_ws;

  const size_t MB = 1024 * 1024;
  size_t o = 4096;  // flags live in [0,4096)
  u16* wWzx = (u16*)(ws + o); o += 4 * MB;   // [L=2][1024][1024] bf16
  u16* wWzh = (u16*)(ws + o); o += 4 * MB;
  u16* wWrx = (u16*)(ws + o); o += 4 * MB;
  u16* wWrh = (u16*)(ws + o); o += 4 * MB;
  u16* wWgx = (u16*)(ws + o); o += 4 * MB;
  u16* wWgh = (u16*)(ws + o); o += 4 * MB;
  u16* wWo  = (u16*)(ws + o); o += 2 * MB;
  u16* Az    = (u16*)(ws + o); o += 32 * MB;  // [16384,1024] bf16 (reused for layer1)
  u16* Ar    = (u16*)(ws + o); o += 32 * MB;
  u16* Ag    = (u16*)(ws + o); o += 32 * MB;
  u16* hist0 = (u16*)(ws + o); o += 32 * MB;
  u16* xbf   = (u16*)(ws + o); o += 32 * MB;  // x bf16; later reused as hist1
  float* h32_0 = (float*)(ws + o); o += 131072;
  float* h32_1 = (float*)(ws + o); o += 131072;
  u16* hbf_0 = (u16*)(ws + o); o += 65536;
  u16* hbf_1 = (u16*)(ws + o); o += 65536;
  u16* rhbf  = (u16*)(ws + o); o += 65536;

  if (ws_size < o) {
    fprintf(stderr, "[gru] INSUFFICIENT WORKSPACE ws=%zu need=%zu\n", ws_size, o);
    return;
  }
  unsigned* flags0 = (unsigned*)(ws + 0);
  unsigned* flags1 = (unsigned*)(ws + 2048);
  hipMemsetAsync(ws, 0, 4096, stream);

  // casts
  castk<<<dim3(8192), dim3(256), 0, stream>>>(Wzx, wWzx, 2097152);
  castk<<<dim3(8192), dim3(256), 0, stream>>>(Wzh, wWzh, 2097152);
  castk<<<dim3(8192), dim3(256), 0, stream>>>(Wrx, wWrx, 2097152);
  castk<<<dim3(8192), dim3(256), 0, stream>>>(Wrh, wWrh, 2097152);
  castk<<<dim3(8192), dim3(256), 0, stream>>>(Wgx, wWgx, 2097152);
  castk<<<dim3(8192), dim3(256), 0, stream>>>(Wgh, wWgh, 2097152);
  castk<<<dim3(4096), dim3(256), 0, stream>>>(Wo, wWo, 1048576);
  castk<<<dim3(65536), dim3(256), 0, stream>>>(x, xbf, 16777216);
  init_h<<<dim3(128), dim3(256), 0, stream>>>(h0, h32_0, h32_1, hbf_0, hbf_1);

  // layer0 input projections
  gemm_nt<1><<<dim3(1024), dim3(256), 0, stream>>>(xbf, wWzx, bz, Az, 16384, 1024, 1024);
  gemm_nt<1><<<dim3(1024), dim3(256), 0, stream>>>(xbf, wWrx, br, Ar, 16384, 1024, 1024);
  gemm_nt<1><<<dim3(1024), dim3(256), 0, stream>>>(xbf, wWgx, bg, Ag, 16384, 1024, 1024);

  // layer0 recurrence
  gru_layer2<<<dim3(128), dim3(128), 0, stream>>>(wWzh, wWrh, wWgh, Az, Ar, Ag, hist0,
                                                  h32_0, hbf_0, rhbf, flags0, 512);

  // layer1 input projections (from h0 history)
  gemm_nt<1><<<dim3(1024), dim3(256), 0, stream>>>(hist0, wWzx + 1048576, bz + 1024, Az, 16384, 1024, 1024);
  gemm_nt<1><<<dim3(1024), dim3(256), 0, stream>>>(hist0, wWrx + 1048576, br + 1024, Ar, 16384, 1024, 1024);
  gemm_nt<1><<<dim3(1024), dim3(256), 0, stream>>>(hist0, wWgx + 1048576, bg + 1024, Ag, 16384, 1024, 1024);

  // layer1 recurrence (hist1 lives in xbf region - x no longer needed)
  gru_layer2<<<dim3(128), dim3(128), 0, stream>>>(wWzh + 1048576, wWrh + 1048576,
                                                  wWgh + 1048576, Az, Ar, Ag, xbf,
                                                  h32_1, hbf_1, rhbf, flags1, 512);

  // output projection
  gemm_nt<0><<<dim3(1024), dim3(256), 0, stream>>>(xbf, wWo, bo, out, 16384, 1024, 1024);

  // final hidden states
  final_h<<<dim3(128), dim3(256), 0, stream>>>(h32_0, h32_1, out + 16777216);
}

// Round 3
// 9267.987 us; speedup vs baseline: 5.4617x; 1.6152x over previous
//
#include <hip/hip_runtime.h>
#include <hip/hip_bf16.h>
#include <cstdio>
#include <cstdint>

// MultilayerGRU: B=32, S=512, I=H=O=1024, L=2
// R3: swizzled LDS staging (no bank conflicts), weights in VGPRs,
//     step-major A layout + register prefetch, manual waitcnt+relaxed flag
//     publish (no wbl2), 2-way MFMA ILP, fast tanh.

typedef float f32x4 __attribute__((ext_vector_type(4)));
typedef __bf16 bf16x8 __attribute__((ext_vector_type(8)));
typedef unsigned short u16;

#define AS1 __attribute__((address_space(1)))
#define AS3 __attribute__((address_space(3)))

__device__ inline u16 f2b(float f) {
  __hip_bfloat16 h = __float2bfloat16(f);
  return *reinterpret_cast<u16*>(&h);
}
__device__ inline float b2f(u16 u) {
  __hip_bfloat16 h;
  *reinterpret_cast<u16*>(&h) = u;
  return __bfloat162float(h);
}
__device__ inline bf16x8 ld8(const u16* p) {
  return *reinterpret_cast<const bf16x8*>(p);
}
__device__ inline f32x4 mfma16(bf16x8 a, bf16x8 b, f32x4 c) {
  return __builtin_amdgcn_mfma_f32_16x16x32_bf16(a, b, c, 0, 0, 0);
}

// plain (L2-cacheable) global->LDS DMA, 16B/lane
__device__ inline void gload_lds16(const void* g, void* l) {
  __builtin_amdgcn_global_load_lds((const AS1 void*)g, (AS3 void*)l, 16, 0, 0);
}
// agent-coherent global->LDS DMA (CPol SC0|SC1): bypass stale L1/L2, read LLC
__device__ inline void gload_lds16c(const void* g, void* l) {
  __builtin_amdgcn_global_load_lds((const AS1 void*)g, (AS3 void*)l, 16, 0, 0x11);
}

// relaxed agent-scope (LLC write-through) u16 store
__device__ inline void st16(u16* p, u16 v) {
  __hip_atomic_store(p, v, __ATOMIC_RELAXED, __HIP_MEMORY_SCOPE_AGENT);
}

// 64 lanes watch 64 packed epoch flags; exit when all >= target
__device__ inline void poll64(unsigned* f, unsigned target, int lane) {
  unsigned* p = f + lane;
  while (true) {
    unsigned v = __hip_atomic_load(p, __ATOMIC_RELAXED, __HIP_MEMORY_SCOPE_AGENT);
    if (__all((int)(v >= target))) break;
    __builtin_amdgcn_s_sleep(1);
  }
}

// ---------------- elementwise helpers ----------------

__global__ void castk(const float* __restrict__ src, u16* __restrict__ dst, int n) {
  int i = blockIdx.x * 256 + threadIdx.x;
  if (i < n) dst[i] = f2b(src[i]);
}

__global__ void init_h(const float* __restrict__ h0, float* __restrict__ h32_0,
                       float* __restrict__ h32_1, u16* __restrict__ hbf_0,
                       u16* __restrict__ hbf_1) {
  int i = blockIdx.x * 256 + threadIdx.x;
  if (i < 32 * 1024) {
    int b = i >> 10, j = i & 1023;
    float v0 = h0[(b * 2 + 0) * 1024 + j];
    float v1 = h0[(b * 2 + 1) * 1024 + j];
    h32_0[i] = v0; hbf_0[i] = f2b(v0);
    h32_1[i] = v1; hbf_1[i] = f2b(v1);
  }
}

__global__ void final_h(const float* __restrict__ h32_0, const float* __restrict__ h32_1,
                        float* __restrict__ out) {
  int i = blockIdx.x * 256 + threadIdx.x;
  if (i < 32 * 1024) {
    int b = i >> 10, j = i & 1023;
    out[(b * 2 + 0) * 1024 + j] = h32_0[i];
    out[(b * 2 + 1) * 1024 + j] = h32_1[i];
  }
}

// ---------------- big NT GEMM: C[m,n] = sum_k A[m,k]*B[n,k] + bias[n] ----------------
// MODE 0: fp32 store at [m][n].  MODE 2: bf16 store transposed-to-step-major:
// m = b*512 + t  ->  store at [(t*32 + b)][n]  (A buffers for the recurrence).

template <int MODE>
__global__ __launch_bounds__(256, 2) void gemm_nt(const u16* __restrict__ A,
                                                  const u16* __restrict__ B,
                                                  const float* __restrict__ bias,
                                                  void* __restrict__ Cout,
                                                  int M, int N, int K) {
  __shared__ __align__(16) u16 As[128 * 32];
  __shared__ __align__(16) u16 Bs[128 * 32];
  const int tid = threadIdx.x;
  const int lane = tid & 63;
  const int wave = tid >> 6;
  const int tilesN = N >> 7;
  const int bm = blockIdx.x / tilesN, bn = blockIdx.x % tilesN;
  const int wr = (wave >> 1) << 6, wc = (wave & 1) << 6;
  const int la = lane & 15, kg = lane >> 4;
  f32x4 acc[4][4] = {};
  const int srow = tid >> 2, skoff = (tid & 3) << 3;
  const u16* Ap = A + (size_t)(bm * 128 + srow) * K + skoff;
  const u16* Bp = B + (size_t)(bn * 128 + srow) * K + skoff;
  for (int k0 = 0; k0 < K; k0 += 32) {
    gload_lds16(Ap + k0,            As + tid * 8);
    gload_lds16(Ap + (size_t)64 * K + k0, As + 2048 + tid * 8);
    gload_lds16(Bp + k0,            Bs + tid * 8);
    gload_lds16(Bp + (size_t)64 * K + k0, Bs + 2048 + tid * 8);
    __syncthreads();
    bf16x8 af[4], bfr[4];
#pragma unroll
    for (int i = 0; i < 4; ++i) af[i] = ld8(As + (wr + i * 16 + la) * 32 + kg * 8);
#pragma unroll
    for (int j = 0; j < 4; ++j) bfr[j] = ld8(Bs + (wc + j * 16 + la) * 32 + kg * 8);
#pragma unroll
    for (int i = 0; i < 4; ++i)
#pragma unroll
      for (int j = 0; j < 4; ++j)
        acc[i][j] = mfma16(af[i], bfr[j], acc[i][j]);
    __syncthreads();
  }
  const int rbase = bm * 128 + wr + kg * 4;
  const int cbase = bn * 128 + wc + la;
#pragma unroll
  for (int i = 0; i < 4; ++i) {
#pragma unroll
    for (int j = 0; j < 4; ++j) {
      int col = cbase + j * 16;
      float bv = bias[col];
#pragma unroll
      for (int e = 0; e < 4; ++e) {
        int row = rbase + i * 16 + e;
        float v = acc[i][j][e] + bv;
        if (MODE == 0) {
          ((float*)Cout)[(size_t)row * N + col] = v;
        } else {
          int tt = row & 511, bb = row >> 9;
          ((u16*)Cout)[((size_t)(tt * 32 + bb)) * N + col] = f2b(v);
        }
      }
    }
  }
}

// ---------------- persistent GRU layer recurrence, v3 ----------------
// 128 blocks x 128 threads. Block = (rt = blockIdx>>6, colT = blockIdx&63).
// Weights held in VGPRs; staged h/rh XOR-swizzled in LDS; A is [t][32][1024]
// and prefetched into registers before the poll.

__global__ __launch_bounds__(128, 1) void gru_layer3(
    const u16* __restrict__ Wz, const u16* __restrict__ Wr, const u16* __restrict__ Wg,
    const u16* __restrict__ Az, const u16* __restrict__ Ar, const u16* __restrict__ Ag,
    u16* __restrict__ hist, float* __restrict__ h32g, u16* __restrict__ hbf,
    u16* __restrict__ rhbf, unsigned* __restrict__ flags, int S) {
  __shared__ __align__(16) u16 LDSh[16 * 1024];
  __shared__ float zloc[256];
  __shared__ float h32loc[256];
  __shared__ float part[256];
  const int tid = threadIdx.x, wave = tid >> 6, lane = tid & 63;
  const int la = lane & 15, kg = lane >> 4;
  const int sw = la & 7;
  const int rt = blockIdx.x >> 6, colT = blockIdx.x & 63;
  const int col = colT * 16 + la;
  unsigned* fl1 = flags + rt * 128;       // stage1 (rhbf ready) epochs [64]
  unsigned* fl2 = flags + rt * 128 + 64;  // stage2 (h ready) epochs [64]

  for (int i = tid; i < 256; i += 128)
    h32loc[i] = h32g[(rt * 16 + (i >> 4)) * 1024 + colT * 16 + (i & 15)];
  __syncthreads();

  // preload this wave's weight slices into registers (stay in VGPRs: fully
  // unrolled constant indexing). wzr: 128 VGPR, wg: 64 VGPR.
  const u16* w1p = (wave ? Wr : Wz) + (size_t)col * 1024 + kg * 8;
  const u16* wgp = Wg + (size_t)col * 1024 + wave * 512 + kg * 8;
  bf16x8 wzr[32], wg[16];
#pragma unroll
  for (int ks = 0; ks < 32; ++ks) wzr[ks] = ld8(w1p + ks * 32);
#pragma unroll
  for (int ks = 0; ks < 16; ++ks) wg[ks] = ld8(wgp + ks * 32);

  const u16* A1 = wave ? Ar : Az;
  const u16* hsrc = hbf + rt * 16 * 1024;
  const u16* rsrc = rhbf + rt * 16 * 1024;
  const int rowb = rt * 16 + kg * 4;  // batch-row base of this lane's outputs

  for (int t = 0; t < S; ++t) {
    // ---- A prefetch: independent of flags, overlaps poll+staging ----
    const u16* A1t = A1 + (size_t)t * 32768;
    u16 a1raw[4];
#pragma unroll
    for (int e = 0; e < 4; ++e) a1raw[e] = A1t[(rowb + e - rt * 16 + rt * 16) * 1024 + col];
    u16 agraw[4] = {0, 0, 0, 0};
    if (wave == 0) {
      const u16* Agt = Ag + (size_t)t * 32768;
#pragma unroll
      for (int e = 0; e < 4; ++e) agraw[e] = Agt[(rowb + e) * 1024 + col];
    }
    // ---- stage 1: z (wave0) and r (wave1) ----
    poll64(fl2, (unsigned)t, lane);
#pragma unroll
    for (int i = 0; i < 16; ++i) {
      int u = i * 2 + wave, r = u >> 1, c = u & 1;
      gload_lds16c(hsrc + r * 1024 + c * 512 + (lane ^ (r & 7)) * 8,
                   LDSh + r * 1024 + c * 512 + lane * 8);
    }
    __syncthreads();  // drains DMA (vmcnt) for both waves
    f32x4 p0 = {0.f, 0.f, 0.f, 0.f}, p1 = {0.f, 0.f, 0.f, 0.f};
#pragma unroll
    for (int ks = 0; ks < 32; ks += 2) {
      p0 = mfma16(ld8(LDSh + la * 1024 + (((ks * 4 + kg) ^ sw) << 3)), wzr[ks], p0);
      p1 = mfma16(ld8(LDSh + la * 1024 + ((((ks + 1) * 4 + kg) ^ sw) << 3)), wzr[ks + 1], p1);
    }
    if (wave == 0) {
#pragma unroll
      for (int e = 0; e < 4; ++e) {
        float pre = p0[e] + p1[e] + b2f(a1raw[e]);
        zloc[(kg * 4 + e) * 16 + la] = 1.f / (1.f + __expf(-pre));
      }
    } else {
#pragma unroll
      for (int e = 0; e < 4; ++e) {
        float pre = p0[e] + p1[e] + b2f(a1raw[e]);
        float rv = 1.f / (1.f + __expf(-pre));
        st16(&rhbf[(rowb + e) * 1024 + col], f2b(rv * h32loc[(kg * 4 + e) * 16 + la]));
      }
      __builtin_amdgcn_s_waitcnt(0);  // r-tile drained to LLC
      if (lane == 0)
        __hip_atomic_store(&fl1[colT], (unsigned)(t + 1), __ATOMIC_RELAXED,
                           __HIP_MEMORY_SCOPE_AGENT);
    }
    __syncthreads();  // wave0 must not DMA over LDSh while wave1 still reads it
    // ---- stage 2: g (split-K over both waves) + h update (wave0) ----
    poll64(fl1, (unsigned)(t + 1), lane);
#pragma unroll
    for (int i = 0; i < 16; ++i) {
      int u = i * 2 + wave, r = u >> 1, c = u & 1;
      gload_lds16c(rsrc + r * 1024 + c * 512 + (lane ^ (r & 7)) * 8,
                   LDSh + r * 1024 + c * 512 + lane * 8);
    }
    __syncthreads();
    f32x4 q0 = {0.f, 0.f, 0.f, 0.f}, q1 = {0.f, 0.f, 0.f, 0.f};
#pragma unroll
    for (int ks = 0; ks < 16; ks += 2) {
      q0 = mfma16(ld8(LDSh + la * 1024 + (((wave * 64 + ks * 4 + kg) ^ sw) << 3)), wg[ks], q0);
      q1 = mfma16(ld8(LDSh + la * 1024 + (((wave * 64 + (ks + 1) * 4 + kg) ^ sw) << 3)), wg[ks + 1], q1);
    }
    if (wave == 1) {
#pragma unroll
      for (int e = 0; e < 4; ++e) part[lane * 4 + e] = q0[e] + q1[e];
    }
    __syncthreads();
    if (wave == 0) {
#pragma unroll
      for (int e = 0; e < 4; ++e) {
        int li = (kg * 4 + e) * 16 + la;
        float gs = q0[e] + q1[e] + part[lane * 4 + e] + b2f(agraw[e]);
        float ex = __expf(2.f * gs);
        float g = 1.f - 2.f / (ex + 1.f);  // tanh, inf-safe
        float z = zloc[li];
        float hn = (1.f - z) * h32loc[li] + z * g;
        h32loc[li] = hn;
        u16 hb = f2b(hn);
        st16(&hbf[(rowb + e) * 1024 + col], hb);
        st16(&hist[(size_t)((rowb + e) * S + t) * 1024 + col], hb);
        if (t == S - 1) h32g[(rowb + e) * 1024 + col] = hn;
      }
      __builtin_amdgcn_s_waitcnt(0);  // h-tile (hbf+hist) drained to LLC
      if (lane == 0)
        __hip_atomic_store(&fl2[colT], (unsigned)(t + 1), __ATOMIC_RELAXED,
                           __HIP_MEMORY_SCOPE_AGENT);
    }
    __syncthreads();  // next stage1 DMA must not overwrite LDSh early
  }
}

// ---------------- host ----------------

extern "C" void kernel_launch(void* const* d_in, const int* in_sizes, int n_in,
                              void* d_out, int out_size, void* d_ws, size_t ws_size,
                              hipStream_t stream) {
  (void)in_sizes; (void)n_in; (void)out_size;
  const float* x   = (const float*)d_in[0];
  const float* h0  = (const float*)d_in[1];
  const float* Wzx = (const float*)d_in[2];
  const float* bz  = (const float*)d_in[3];
  const float* Wzh = (const float*)d_in[4];
  const float* Wrx = (const float*)d_in[5];
  const float* br  = (const float*)d_in[6];
  const float* Wrh = (const float*)d_in[7];
  const float* Wgx = (const float*)d_in[8];
  const float* bg  = (const float*)d_in[9];
  const float* Wgh = (const float*)d_in[10];
  const float* Wo  = (const float*)d_in[11];
  const float* bo  = (const float*)d_in[12];
  float* out = (float*)d_out;
  char* ws = (char*)d_ws;

  const size_t MB = 1024 * 1024;
  size_t o = 4096;  // flags live in [0,4096)
  u16* wWzx = (u16*)(ws + o); o += 4 * MB;   // [L=2][1024][1024] bf16
  u16* wWzh = (u16*)(ws + o); o += 4 * MB;
  u16* wWrx = (u16*)(ws + o); o += 4 * MB;
  u16* wWrh = (u16*)(ws + o); o += 4 * MB;
  u16* wWgx = (u16*)(ws + o); o += 4 * MB;
  u16* wWgh = (u16*)(ws + o); o += 4 * MB;
  u16* wWo  = (u16*)(ws + o); o += 2 * MB;
  u16* Az    = (u16*)(ws + o); o += 32 * MB;  // [512][32][1024] bf16 step-major
  u16* Ar    = (u16*)(ws + o); o += 32 * MB;
  u16* Ag    = (u16*)(ws + o); o += 32 * MB;
  u16* hist0 = (u16*)(ws + o); o += 32 * MB;  // [b*S+t][1024]
  u16* xbf   = (u16*)(ws + o); o += 32 * MB;  // x bf16; later reused as hist1
  float* h32_0 = (float*)(ws + o); o += 131072;
  float* h32_1 = (float*)(ws + o); o += 131072;
  u16* hbf_0 = (u16*)(ws + o); o += 65536;
  u16* hbf_1 = (u16*)(ws + o); o += 65536;
  u16* rhbf  = (u16*)(ws + o); o += 65536;

  if (ws_size < o) {
    fprintf(stderr, "[gru] INSUFFICIENT WORKSPACE ws=%zu need=%zu\n", ws_size, o);
    return;
  }
  unsigned* flags0 = (unsigned*)(ws + 0);
  unsigned* flags1 = (unsigned*)(ws + 2048);
  hipMemsetAsync(ws, 0, 4096, stream);

  // casts
  castk<<<dim3(8192), dim3(256), 0, stream>>>(Wzx, wWzx, 2097152);
  castk<<<dim3(8192), dim3(256), 0, stream>>>(Wzh, wWzh, 2097152);
  castk<<<dim3(8192), dim3(256), 0, stream>>>(Wrx, wWrx, 2097152);
  castk<<<dim3(8192), dim3(256), 0, stream>>>(Wrh, wWrh, 2097152);
  castk<<<dim3(8192), dim3(256), 0, stream>>>(Wgx, wWgx, 2097152);
  castk<<<dim3(8192), dim3(256), 0, stream>>>(Wgh, wWgh, 2097152);
  castk<<<dim3(4096), dim3(256), 0, stream>>>(Wo, wWo, 1048576);
  castk<<<dim3(65536), dim3(256), 0, stream>>>(x, xbf, 16777216);
  init_h<<<dim3(128), dim3(256), 0, stream>>>(h0, h32_0, h32_1, hbf_0, hbf_1);

  // layer0 input projections (step-major output)
  gemm_nt<2><<<dim3(1024), dim3(256), 0, stream>>>(xbf, wWzx, bz, Az, 16384, 1024, 1024);
  gemm_nt<2><<<dim3(1024), dim3(256), 0, stream>>>(xbf, wWrx, br, Ar, 16384, 1024, 1024);
  gemm_nt<2><<<dim3(1024), dim3(256), 0, stream>>>(xbf, wWgx, bg, Ag, 16384, 1024, 1024);

  // layer0 recurrence
  gru_layer3<<<dim3(128), dim3(128), 0, stream>>>(wWzh, wWrh, wWgh, Az, Ar, Ag, hist0,
                                                  h32_0, hbf_0, rhbf, flags0, 512);

  // layer1 input projections (from h0 history)
  gemm_nt<2><<<dim3(1024), dim3(256), 0, stream>>>(hist0, wWzx + 1048576, bz + 1024, Az, 16384, 1024, 1024);
  gemm_nt<2><<<dim3(1024), dim3(256), 0, stream>>>(hist0, wWrx + 1048576, br + 1024, Ar, 16384, 1024, 1024);
  gemm_nt<2><<<dim3(1024), dim3(256), 0, stream>>>(hist0, wWgx + 1048576, bg + 1024, Ag, 16384, 1024, 1024);

  // layer1 recurrence (hist1 lives in xbf region - x no longer needed)
  gru_layer3<<<dim3(128), dim3(128), 0, stream>>>(wWzh + 1048576, wWrh + 1048576,
                                                  wWgh + 1048576, Az, Ar, Ag, xbf,
                                                  h32_1, hbf_1, rhbf, flags1, 512);

  // output projection
  gemm_nt<0><<<dim3(1024), dim3(256), 0, stream>>>(xbf, wWo, bo, out, 16384, 1024, 1024);

  // final hidden states
  final_h<<<dim3(128), dim3(256), 0, stream>>>(h32_0, h32_1, out + 16777216);
}

// Round 4
// 8292.470 us; speedup vs baseline: 6.1042x; 1.1176x over previous
//
#include <hip/hip_runtime.h>
#include <hip/hip_bf16.h>
#include <cstdio>
#include <cstdint>

// MultilayerGRU: B=32, S=512, I=H=O=1024, L=2
// R4: DMA coherence scope fixed to agent (SC1=0x10, was system 0x11 -> HBM
//     bypass of LLC). hist stores plain+after-publish (off critical path).

typedef float f32x4 __attribute__((ext_vector_type(4)));
typedef __bf16 bf16x8 __attribute__((ext_vector_type(8)));
typedef unsigned short u16;

#define AS1 __attribute__((address_space(1)))
#define AS3 __attribute__((address_space(3)))

__device__ inline u16 f2b(float f) {
  __hip_bfloat16 h = __float2bfloat16(f);
  return *reinterpret_cast<u16*>(&h);
}
__device__ inline float b2f(u16 u) {
  __hip_bfloat16 h;
  *reinterpret_cast<u16*>(&h) = u;
  return __bfloat162float(h);
}
__device__ inline bf16x8 ld8(const u16* p) {
  return *reinterpret_cast<const bf16x8*>(p);
}
__device__ inline f32x4 mfma16(bf16x8 a, bf16x8 b, f32x4 c) {
  return __builtin_amdgcn_mfma_f32_16x16x32_bf16(a, b, c, 0, 0, 0);
}

// plain (L2-cacheable) global->LDS DMA, 16B/lane
__device__ inline void gload_lds16(const void* g, void* l) {
  __builtin_amdgcn_global_load_lds((const AS1 void*)g, (AS3 void*)l, 16, 0, 0);
}
// agent-scope global->LDS DMA (CPol SC1 only = device scope): bypasses the
// potentially-stale per-XCD L2 but is served by the LLC (agent coherence pt).
__device__ inline void gload_lds16c(const void* g, void* l) {
  __builtin_amdgcn_global_load_lds((const AS1 void*)g, (AS3 void*)l, 16, 0, 0x10);
}

// relaxed agent-scope (LLC write-through) u16 store
__device__ inline void st16(u16* p, u16 v) {
  __hip_atomic_store(p, v, __ATOMIC_RELAXED, __HIP_MEMORY_SCOPE_AGENT);
}

// 64 lanes watch 64 packed epoch flags; exit when all >= target
__device__ inline void poll64(unsigned* f, unsigned target, int lane) {
  unsigned* p = f + lane;
  while (true) {
    unsigned v = __hip_atomic_load(p, __ATOMIC_RELAXED, __HIP_MEMORY_SCOPE_AGENT);
    if (__all((int)(v >= target))) break;
    __builtin_amdgcn_s_sleep(1);
  }
}

// ---------------- elementwise helpers ----------------

__global__ void castk(const float* __restrict__ src, u16* __restrict__ dst, int n) {
  int i = blockIdx.x * 256 + threadIdx.x;
  if (i < n) dst[i] = f2b(src[i]);
}

__global__ void init_h(const float* __restrict__ h0, float* __restrict__ h32_0,
                       float* __restrict__ h32_1, u16* __restrict__ hbf_0,
                       u16* __restrict__ hbf_1) {
  int i = blockIdx.x * 256 + threadIdx.x;
  if (i < 32 * 1024) {
    int b = i >> 10, j = i & 1023;
    float v0 = h0[(b * 2 + 0) * 1024 + j];
    float v1 = h0[(b * 2 + 1) * 1024 + j];
    h32_0[i] = v0; hbf_0[i] = f2b(v0);
    h32_1[i] = v1; hbf_1[i] = f2b(v1);
  }
}

__global__ void final_h(const float* __restrict__ h32_0, const float* __restrict__ h32_1,
                        float* __restrict__ out) {
  int i = blockIdx.x * 256 + threadIdx.x;
  if (i < 32 * 1024) {
    int b = i >> 10, j = i & 1023;
    out[(b * 2 + 0) * 1024 + j] = h32_0[i];
    out[(b * 2 + 1) * 1024 + j] = h32_1[i];
  }
}

// ---------------- big NT GEMM: C[m,n] = sum_k A[m,k]*B[n,k] + bias[n] ----------------
// MODE 0: fp32 store at [m][n].  MODE 2: bf16 store transposed-to-step-major:
// m = b*512 + t  ->  store at [(t*32 + b)][n]  (A buffers for the recurrence).

template <int MODE>
__global__ __launch_bounds__(256, 2) void gemm_nt(const u16* __restrict__ A,
                                                  const u16* __restrict__ B,
                                                  const float* __restrict__ bias,
                                                  void* __restrict__ Cout,
                                                  int M, int N, int K) {
  __shared__ __align__(16) u16 As[128 * 32];
  __shared__ __align__(16) u16 Bs[128 * 32];
  const int tid = threadIdx.x;
  const int lane = tid & 63;
  const int wave = tid >> 6;
  const int tilesN = N >> 7;
  const int bm = blockIdx.x / tilesN, bn = blockIdx.x % tilesN;
  const int wr = (wave >> 1) << 6, wc = (wave & 1) << 6;
  const int la = lane & 15, kg = lane >> 4;
  f32x4 acc[4][4] = {};
  const int srow = tid >> 2, skoff = (tid & 3) << 3;
  const u16* Ap = A + (size_t)(bm * 128 + srow) * K + skoff;
  const u16* Bp = B + (size_t)(bn * 128 + srow) * K + skoff;
  for (int k0 = 0; k0 < K; k0 += 32) {
    gload_lds16(Ap + k0,            As + tid * 8);
    gload_lds16(Ap + (size_t)64 * K + k0, As + 2048 + tid * 8);
    gload_lds16(Bp + k0,            Bs + tid * 8);
    gload_lds16(Bp + (size_t)64 * K + k0, Bs + 2048 + tid * 8);
    __syncthreads();
    bf16x8 af[4], bfr[4];
#pragma unroll
    for (int i = 0; i < 4; ++i) af[i] = ld8(As + (wr + i * 16 + la) * 32 + kg * 8);
#pragma unroll
    for (int j = 0; j < 4; ++j) bfr[j] = ld8(Bs + (wc + j * 16 + la) * 32 + kg * 8);
#pragma unroll
    for (int i = 0; i < 4; ++i)
#pragma unroll
      for (int j = 0; j < 4; ++j)
        acc[i][j] = mfma16(af[i], bfr[j], acc[i][j]);
    __syncthreads();
  }
  const int rbase = bm * 128 + wr + kg * 4;
  const int cbase = bn * 128 + wc + la;
#pragma unroll
  for (int i = 0; i < 4; ++i) {
#pragma unroll
    for (int j = 0; j < 4; ++j) {
      int col = cbase + j * 16;
      float bv = bias[col];
#pragma unroll
      for (int e = 0; e < 4; ++e) {
        int row = rbase + i * 16 + e;
        float v = acc[i][j][e] + bv;
        if (MODE == 0) {
          ((float*)Cout)[(size_t)row * N + col] = v;
        } else {
          int tt = row & 511, bb = row >> 9;
          ((u16*)Cout)[((size_t)(tt * 32 + bb)) * N + col] = f2b(v);
        }
      }
    }
  }
}

// ---------------- persistent GRU layer recurrence, v4 ----------------
// 128 blocks x 128 threads. Block = (rt = blockIdx>>6, colT = blockIdx&63).
// Weights in VGPRs; staged h/rh XOR-swizzled in LDS via agent-scope DMA;
// A is [t][32][1024], register-prefetched before the poll. hist stores are
// plain cached and issued after the flag publish.

__global__ __launch_bounds__(128, 1) void gru_layer4(
    const u16* __restrict__ Wz, const u16* __restrict__ Wr, const u16* __restrict__ Wg,
    const u16* __restrict__ Az, const u16* __restrict__ Ar, const u16* __restrict__ Ag,
    u16* __restrict__ hist, float* __restrict__ h32g, u16* __restrict__ hbf,
    u16* __restrict__ rhbf, unsigned* __restrict__ flags, int S) {
  __shared__ __align__(16) u16 LDSh[16 * 1024];
  __shared__ float zloc[256];
  __shared__ float h32loc[256];
  __shared__ float part[256];
  const int tid = threadIdx.x, wave = tid >> 6, lane = tid & 63;
  const int la = lane & 15, kg = lane >> 4;
  const int sw = la & 7;
  const int rt = blockIdx.x >> 6, colT = blockIdx.x & 63;
  const int col = colT * 16 + la;
  unsigned* fl1 = flags + rt * 128;       // stage1 (rhbf ready) epochs [64]
  unsigned* fl2 = flags + rt * 128 + 64;  // stage2 (h ready) epochs [64]

  for (int i = tid; i < 256; i += 128)
    h32loc[i] = h32g[(rt * 16 + (i >> 4)) * 1024 + colT * 16 + (i & 15)];
  __syncthreads();

  // preload this wave's weight slices into registers. wzr: 128 VGPR, wg: 64.
  const u16* w1p = (wave ? Wr : Wz) + (size_t)col * 1024 + kg * 8;
  const u16* wgp = Wg + (size_t)col * 1024 + wave * 512 + kg * 8;
  bf16x8 wzr[32], wg[16];
#pragma unroll
  for (int ks = 0; ks < 32; ++ks) wzr[ks] = ld8(w1p + ks * 32);
#pragma unroll
  for (int ks = 0; ks < 16; ++ks) wg[ks] = ld8(wgp + ks * 32);

  const u16* A1 = wave ? Ar : Az;
  const u16* hsrc = hbf + rt * 16 * 1024;
  const u16* rsrc = rhbf + rt * 16 * 1024;
  const int rowb = rt * 16 + kg * 4;  // batch-row base of this lane's outputs

  for (int t = 0; t < S; ++t) {
    // ---- A prefetch: independent of flags, overlaps poll+staging ----
    const u16* A1t = A1 + (size_t)t * 32768;
    u16 a1raw[4];
#pragma unroll
    for (int e = 0; e < 4; ++e) a1raw[e] = A1t[(rowb + e) * 1024 + col];
    u16 agraw[4] = {0, 0, 0, 0};
    if (wave == 0) {
      const u16* Agt = Ag + (size_t)t * 32768;
#pragma unroll
      for (int e = 0; e < 4; ++e) agraw[e] = Agt[(rowb + e) * 1024 + col];
    }
    // ---- stage 1: z (wave0) and r (wave1) ----
    poll64(fl2, (unsigned)t, lane);
#pragma unroll
    for (int i = 0; i < 16; ++i) {
      int u = i * 2 + wave, r = u >> 1, c = u & 1;
      gload_lds16c(hsrc + r * 1024 + c * 512 + (lane ^ (r & 7)) * 8,
                   LDSh + r * 1024 + c * 512 + lane * 8);
    }
    __syncthreads();  // drains DMA (vmcnt) for both waves
    f32x4 p0 = {0.f, 0.f, 0.f, 0.f}, p1 = {0.f, 0.f, 0.f, 0.f};
#pragma unroll
    for (int ks = 0; ks < 32; ks += 2) {
      p0 = mfma16(ld8(LDSh + la * 1024 + (((ks * 4 + kg) ^ sw) << 3)), wzr[ks], p0);
      p1 = mfma16(ld8(LDSh + la * 1024 + ((((ks + 1) * 4 + kg) ^ sw) << 3)), wzr[ks + 1], p1);
    }
    if (wave == 0) {
#pragma unroll
      for (int e = 0; e < 4; ++e) {
        float pre = p0[e] + p1[e] + b2f(a1raw[e]);
        zloc[(kg * 4 + e) * 16 + la] = 1.f / (1.f + __expf(-pre));
      }
    } else {
#pragma unroll
      for (int e = 0; e < 4; ++e) {
        float pre = p0[e] + p1[e] + b2f(a1raw[e]);
        float rv = 1.f / (1.f + __expf(-pre));
        st16(&rhbf[(rowb + e) * 1024 + col], f2b(rv * h32loc[(kg * 4 + e) * 16 + la]));
      }
      __builtin_amdgcn_s_waitcnt(0);  // r-tile drained to LLC
      if (lane == 0)
        __hip_atomic_store(&fl1[colT], (unsigned)(t + 1), __ATOMIC_RELAXED,
                           __HIP_MEMORY_SCOPE_AGENT);
    }
    __syncthreads();  // wave0 must not DMA over LDSh while wave1 still reads it
    // ---- stage 2: g (split-K over both waves) + h update (wave0) ----
    poll64(fl1, (unsigned)(t + 1), lane);
#pragma unroll
    for (int i = 0; i < 16; ++i) {
      int u = i * 2 + wave, r = u >> 1, c = u & 1;
      gload_lds16c(rsrc + r * 1024 + c * 512 + (lane ^ (r & 7)) * 8,
                   LDSh + r * 1024 + c * 512 + lane * 8);
    }
    __syncthreads();
    f32x4 q0 = {0.f, 0.f, 0.f, 0.f}, q1 = {0.f, 0.f, 0.f, 0.f};
#pragma unroll
    for (int ks = 0; ks < 16; ks += 2) {
      q0 = mfma16(ld8(LDSh + la * 1024 + (((wave * 64 + ks * 4 + kg) ^ sw) << 3)), wg[ks], q0);
      q1 = mfma16(ld8(LDSh + la * 1024 + (((wave * 64 + (ks + 1) * 4 + kg) ^ sw) << 3)), wg[ks + 1], q1);
    }
    if (wave == 1) {
#pragma unroll
      for (int e = 0; e < 4; ++e) part[lane * 4 + e] = q0[e] + q1[e];
    }
    __syncthreads();
    if (wave == 0) {
      float hnv[4];
      u16 hbv[4];
#pragma unroll
      for (int e = 0; e < 4; ++e) {
        int li = (kg * 4 + e) * 16 + la;
        float gs = q0[e] + q1[e] + part[lane * 4 + e] + b2f(agraw[e]);
        float ex = __expf(2.f * gs);
        float g = 1.f - 2.f / (ex + 1.f);  // tanh, inf-safe
        float z = zloc[li];
        float hn = (1.f - z) * h32loc[li] + z * g;
        h32loc[li] = hn;
        hnv[e] = hn;
        hbv[e] = f2b(hn);
        st16(&hbf[(rowb + e) * 1024 + col], hbv[e]);  // critical-path publish
      }
      __builtin_amdgcn_s_waitcnt(0);  // h-tile (hbf only) drained to LLC
      if (lane == 0)
        __hip_atomic_store(&fl2[colT], (unsigned)(t + 1), __ATOMIC_RELAXED,
                           __HIP_MEMORY_SCOPE_AGENT);
      // off-critical-path: history (read only by later dispatches; kernel-
      // boundary flush provides visibility) + final-state snapshot
#pragma unroll
      for (int e = 0; e < 4; ++e) {
        hist[(size_t)((rowb + e) * S + t) * 1024 + col] = hbv[e];
        if (t == S - 1) h32g[(rowb + e) * 1024 + col] = hnv[e];
      }
    }
    __syncthreads();  // next stage1 DMA must not overwrite LDSh early
  }
}

// ---------------- host ----------------

extern "C" void kernel_launch(void* const* d_in, const int* in_sizes, int n_in,
                              void* d_out, int out_size, void* d_ws, size_t ws_size,
                              hipStream_t stream) {
  (void)in_sizes; (void)n_in; (void)out_size;
  const float* x   = (const float*)d_in[0];
  const float* h0  = (const float*)d_in[1];
  const float* Wzx = (const float*)d_in[2];
  const float* bz  = (const float*)d_in[3];
  const float* Wzh = (const float*)d_in[4];
  const float* Wrx = (const float*)d_in[5];
  const float* br  = (const float*)d_in[6];
  const float* Wrh = (const float*)d_in[7];
  const float* Wgx = (const float*)d_in[8];
  const float* bg  = (const float*)d_in[9];
  const float* Wgh = (const float*)d_in[10];
  const float* Wo  = (const float*)d_in[11];
  const float* bo  = (const float*)d_in[12];
  float* out = (float*)d_out;
  char* ws = (char*)d_ws;

  const size_t MB = 1024 * 1024;
  size_t o = 4096;  // flags live in [0,4096)
  u16* wWzx = (u16*)(ws + o); o += 4 * MB;   // [L=2][1024][1024] bf16
  u16* wWzh = (u16*)(ws + o); o += 4 * MB;
  u16* wWrx = (u16*)(ws + o); o += 4 * MB;
  u16* wWrh = (u16*)(ws + o); o += 4 * MB;
  u16* wWgx = (u16*)(ws + o); o += 4 * MB;
  u16* wWgh = (u16*)(ws + o); o += 4 * MB;
  u16* wWo  = (u16*)(ws + o); o += 2 * MB;
  u16* Az    = (u16*)(ws + o); o += 32 * MB;  // [512][32][1024] bf16 step-major
  u16* Ar    = (u16*)(ws + o); o += 32 * MB;
  u16* Ag    = (u16*)(ws + o); o += 32 * MB;
  u16* hist0 = (u16*)(ws + o); o += 32 * MB;  // [b*S+t][1024]
  u16* xbf   = (u16*)(ws + o); o += 32 * MB;  // x bf16; later reused as hist1
  float* h32_0 = (float*)(ws + o); o += 131072;
  float* h32_1 = (float*)(ws + o); o += 131072;
  u16* hbf_0 = (u16*)(ws + o); o += 65536;
  u16* hbf_1 = (u16*)(ws + o); o += 65536;
  u16* rhbf  = (u16*)(ws + o); o += 65536;

  if (ws_size < o) {
    fprintf(stderr, "[gru] INSUFFICIENT WORKSPACE ws=%zu need=%zu\n", ws_size, o);
    return;
  }
  unsigned* flags0 = (unsigned*)(ws + 0);
  unsigned* flags1 = (unsigned*)(ws + 2048);
  hipMemsetAsync(ws, 0, 4096, stream);

  // casts
  castk<<<dim3(8192), dim3(256), 0, stream>>>(Wzx, wWzx, 2097152);
  castk<<<dim3(8192), dim3(256), 0, stream>>>(Wzh, wWzh, 2097152);
  castk<<<dim3(8192), dim3(256), 0, stream>>>(Wrx, wWrx, 2097152);
  castk<<<dim3(8192), dim3(256), 0, stream>>>(Wrh, wWrh, 2097152);
  castk<<<dim3(8192), dim3(256), 0, stream>>>(Wgx, wWgx, 2097152);
  castk<<<dim3(8192), dim3(256), 0, stream>>>(Wgh, wWgh, 2097152);
  castk<<<dim3(4096), dim3(256), 0, stream>>>(Wo, wWo, 1048576);
  castk<<<dim3(65536), dim3(256), 0, stream>>>(x, xbf, 16777216);
  init_h<<<dim3(128), dim3(256), 0, stream>>>(h0, h32_0, h32_1, hbf_0, hbf_1);

  // layer0 input projections (step-major output)
  gemm_nt<2><<<dim3(1024), dim3(256), 0, stream>>>(xbf, wWzx, bz, Az, 16384, 1024, 1024);
  gemm_nt<2><<<dim3(1024), dim3(256), 0, stream>>>(xbf, wWrx, br, Ar, 16384, 1024, 1024);
  gemm_nt<2><<<dim3(1024), dim3(256), 0, stream>>>(xbf, wWgx, bg, Ag, 16384, 1024, 1024);

  // layer0 recurrence
  gru_layer4<<<dim3(128), dim3(128), 0, stream>>>(wWzh, wWrh, wWgh, Az, Ar, Ag, hist0,
                                                  h32_0, hbf_0, rhbf, flags0, 512);

  // layer1 input projections (from h0 history)
  gemm_nt<2><<<dim3(1024), dim3(256), 0, stream>>>(hist0, wWzx + 1048576, bz + 1024, Az, 16384, 1024, 1024);
  gemm_nt<2><<<dim3(1024), dim3(256), 0, stream>>>(hist0, wWrx + 1048576, br + 1024, Ar, 16384, 1024, 1024);
  gemm_nt<2><<<dim3(1024), dim3(256), 0, stream>>>(hist0, wWgx + 1048576, bg + 1024, Ag, 16384, 1024, 1024);

  // layer1 recurrence (hist1 lives in xbf region - x no longer needed)
  gru_layer4<<<dim3(128), dim3(128), 0, stream>>>(wWzh + 1048576, wWrh + 1048576,
                                                  wWgh + 1048576, Az, Ar, Ag, xbf,
                                                  h32_1, hbf_1, rhbf, flags1, 512);

  // output projection
  gemm_nt<0><<<dim3(1024), dim3(256), 0, stream>>>(xbf, wWo, bo, out, 16384, 1024, 1024);

  // final hidden states
  final_h<<<dim3(128), dim3(256), 0, stream>>>(h32_0, h32_1, out + 16777216);
}